// Round 3
// baseline (3921.709 us; speedup 1.0000x reference)
//
#include <hip/hip_runtime.h>

typedef _Float16 v8h __attribute__((ext_vector_type(8)));
typedef float    v4f __attribute__((ext_vector_type(4)));

#define MFMA16(A,B,C) __builtin_amdgcn_mfma_f32_16x16x32_f16((A),(B),(C),0,0,0)

#define RPB 4
#define TT  256
#define HH  64
#define KST 136        // f16 stride per A row: k 0-63 = ha, 64-127 = hb, 8 pad
#define SGN -1.44269504f   // -log2(e): sigma(z) = rcp(1 + exp2(z*SGN_scaled))
#define GTS -2.88539008f   // -2*log2(e): tanh(z) = 2*sigma(2z)-1
#define TSC2 -2.88539008f  // tanh(c) = 2*rcp(1+exp2(c*TSC2))-1

// R3 = R2 resubmission (container failed twice = infra flake; kernel
// re-audited: uniform barriers, per-(row,col) single-writer hs, finite f16
// stores, ~7.3KB LDS, VGPR fits bound-4).
// R2 theory: occupancy was grid-limited (512 blocks = 2/CU) and the
// recurrence is latency-bound (no pipe >70%). RPB 8->4: 1024 blocks =
// 4 blocks/CU = 4 waves/SIMD interleaving the serial chain; per-lane
// pointwise halves (8 sig + 2 tanh); MFMA/wave unchanged (C rows 4-15
// duplicate rows 0-3 via A-frag dup-read, no LDS duplication).
__global__ __launch_bounds__(256, 4)
void lstm2_kernel(const float* __restrict__ x,     // [4096][256]
                  const float* __restrict__ Wih0,  // [256][1]
                  const float* __restrict__ Whh0,  // [256][64]
                  const float* __restrict__ bih0,
                  const float* __restrict__ bhh0,
                  const float* __restrict__ Wih1,  // [256][64]
                  const float* __restrict__ Whh1,  // [256][64]
                  const float* __restrict__ bih1,
                  const float* __restrict__ bhh1,
                  const float* __restrict__ Wlin,  // [64][64]
                  const float* __restrict__ blin,
                  float* __restrict__ out)         // [4096][64]
{
    __shared__ __align__(16) float xl[TT][RPB];        // 4 KB
    __shared__ __align__(16) _Float16 hs[2][RPB][KST]; // 2.1 KB (no dup rows)
    __shared__ float hbF[RPB][HH];                     // 1 KB

    const int tid  = threadIdx.x;
    const int w    = tid >> 6;
    const int l15  = tid & 15;
    const int l3   = tid & 3;          // A-frag row (dup-read: rows 4-15 -> 0-3)
    const int q    = (tid & 63) >> 4;
    const int row0 = (int)blockIdx.x * RPB;
    const int jj   = w * 16 + l15;
    const bool isA = (q < 2);          // q<2: layer-0 lanes; q>=2: layer-1 lanes
    const int  mr  = (q & 1) * 2;      // my pointwise row base (0 or 2), 2 rows

    // coalesced global read, strided (one-time) LDS write
    for (int idx = tid; idx < RPB * TT; idx += 256) {
        int m = idx >> 8, t = idx & 255;
        xl[t][m] = x[(row0 + m) * TT + t];
    }
    for (int idx = tid; idx < 2 * RPB * KST; idx += 256)
        ((_Float16*)hs)[idx] = (_Float16)0.f;

    // sigma on the trans unit; t is the prescaled MFMA acc (= -z*log2e)
    auto sig = [&](float t) -> float {
        return __builtin_amdgcn_rcpf(1.0f + __builtin_exp2f(t));
    };
    // tanh via hardware exp2+rcp (near-exact, no gather)
    auto tanhf_fast = [&](float c) -> float {
        return fmaf(2.f, __builtin_amdgcn_rcpf(1.f + __builtin_exp2f(c * TSC2)), -1.f);
    };

    // ---- register-stationary weights, prescaled into exp2-argument space ----
    float wi0s[4], b0s[4];
    v4f   b1v[4];
    v8h wh0[4][2], wi1[4][2], wh1[4][2];
    #pragma unroll
    for (int tau = 0; tau < 4; tau++) {
        float sc = (tau == 2) ? GTS : SGN;
        int n = tau * 64 + jj;
        wi0s[tau] = Wih0[n] * sc;
        b0s[tau]  = (bih0[n] + bhh0[n]) * sc;
        float b1  = (bih1[n] + bhh1[n]) * sc;
        b1v[tau]  = (v4f){b1, b1, b1, b1};
        #pragma unroll
        for (int kk = 0; kk < 2; kk++) {
            int k0 = kk * 32 + q * 8;   // B-frag: B[k0..k0+7][n=lane&15]
            v8h a, b, c;
            #pragma unroll
            for (int j = 0; j < 8; j++) {
                a[j] = (_Float16)(Whh0[n * HH + k0 + j] * sc);
                b[j] = (_Float16)(Wih1[n * HH + k0 + j] * sc);
                c[j] = (_Float16)(Whh1[n * HH + k0 + j] * sc);
            }
            wh0[tau][kk] = a; wi1[tau][kk] = b; wh1[tau][kk] = c;
        }
    }

    float cs[2] = {0.f, 0.f};  // c-state of MY layer, rows mr..mr+1
    __syncthreads();

    // ---- prologue t=0: ha(0) from x(0) only (written by q<2 lanes) ----
    if (isA) {
        #pragma unroll
        for (int r = 0; r < 2; r++) {
            int m = mr + r;
            float xv = xl[0][m];
            float iv = sig(fmaf(xv, wi0s[0], b0s[0]));
            float gv = fmaf(2.f, sig(fmaf(xv, wi0s[2], b0s[2])), -1.f);
            float ov = sig(fmaf(xv, wi0s[3], b0s[3]));
            cs[r] = iv * gv;
            hs[0][m][jj] = (_Float16)(ov * tanhf_fast(cs[r]));
        }
    }
    __syncthreads();

    // step k: reads buf[p] {ha(k-1), hb(k-2)}, writes buf[pw] {ha(k), hb(k-1)}
    auto step = [&](int k, int p, int pw, bool last) {
        v8h a0 = *(const v8h*)&hs[p][l3][q * 8];          // ha k 0-31
        v8h a1 = *(const v8h*)&hs[p][l3][32 + q * 8];     // ha k 32-63
        v8h b0 = *(const v8h*)&hs[p][l3][64 + q * 8];     // hb k 0-31
        v8h b1 = *(const v8h*)&hs[p][l3][96 + q * 8];     // hb k 32-63
        int kx = (k < TT) ? k : (TT - 1);                 // k=256: junk x, unused
        v4f xv = *(const v4f*)&xl[kx][0];                 // rows 0-3

        v4f acc0[4], acc1[4];
        #pragma unroll
        for (int tau = 0; tau < 4; tau++) {
            #pragma unroll
            for (int r = 0; r < 4; r++) acc0[tau][r] = fmaf(xv[r], wi0s[tau], b0s[tau]);
            acc1[tau] = MFMA16(a0, wi1[tau][0], b1v[tau]);  // bias as C operand
        }
        #pragma unroll
        for (int tau = 0; tau < 4; tau++) {
            acc0[tau] = MFMA16(a0, wh0[tau][0], acc0[tau]);
            acc0[tau] = MFMA16(a1, wh0[tau][1], acc0[tau]);
            acc1[tau] = MFMA16(a1, wi1[tau][1], acc1[tau]);
            acc1[tau] = MFMA16(b0, wh1[tau][0], acc1[tau]);
            acc1[tau] = MFMA16(b1, wh1[tau][1], acc1[tau]);
        }

        // my gates: q<2 -> layer0; q>=2 -> layer1. acc reg index == batch row
        // (C row = q*4+reg; A rows dup mod 4 -> batch row = reg).
        v4f g0 = isA ? acc0[0] : acc1[0];
        v4f g1 = isA ? acc0[1] : acc1[1];
        v4f g2 = isA ? acc0[2] : acc1[2];
        v4f g3 = isA ? acc0[3] : acc1[3];

        // stage 1: all 8 sigma issued together (trans-unit latency overlap)
        float sv0[2], sv1[2], sv2[2], sv3[2];
        #pragma unroll
        for (int r = 0; r < 2; r++) {
            sv0[r] = sig(g0[mr + r]);
            sv1[r] = sig(g1[mr + r]);
            sv2[r] = sig(g2[mr + r]);
            sv3[r] = sig(g3[mr + r]);
        }

        _Float16* wp = &hs[pw][mr][isA ? jj : (64 + jj)];

        // stage 2: c update, trans tanh, h write (single LDS write per value)
        #pragma unroll
        for (int r = 0; r < 2; r++) {
            float iv = sv0[r];
            float fv = sv1[r];
            float gv = fmaf(2.f, sv2[r], -1.f);
            float ov = sv3[r];
            cs[r] = fmaf(fv, cs[r], iv * gv);
            float hv = ov * tanhf_fast(cs[r]);
            wp[r * KST] = (_Float16)hv;
            if (last && !isA) hbF[mr + r][jj] = hv;
        }
        __syncthreads();
    };

    // k = 1..256 (k=256 = layer-1-only epilogue; its ha output junk-but-finite)
    for (int k = 1; k <= TT; k += 2) {
        step(k,     0, 1, false);
        step(k + 1, 1, 0, (k + 1) == TT);
    }

    // ---- out[m][n] = hbF[m][:] . Wlin[n][:] + blin[n] ----
    int m = tid >> 6;             // 0..3
    int n = tid & 63;
    float ao = blin[n];
    #pragma unroll 8
    for (int j = 0; j < HH; j++)
        ao = fmaf(hbF[m][j], Wlin[n * HH + j], ao);
    out[(row0 + m) * HH + n] = ao;
}

extern "C" void kernel_launch(void* const* d_in, const int* in_sizes, int n_in,
                              void* d_out, int out_size, void* d_ws, size_t ws_size,
                              hipStream_t stream) {
    const float* x    = (const float*)d_in[0];
    const float* Wih0 = (const float*)d_in[1];
    const float* Whh0 = (const float*)d_in[2];
    const float* bih0 = (const float*)d_in[3];
    const float* bhh0 = (const float*)d_in[4];
    const float* Wih1 = (const float*)d_in[5];
    const float* Whh1 = (const float*)d_in[6];
    const float* bih1 = (const float*)d_in[7];
    const float* bhh1 = (const float*)d_in[8];
    const float* Wlin = (const float*)d_in[9];
    const float* blin = (const float*)d_in[10];
    // 4096 rows / 4 per block = 1024 blocks = 4 independent blocks/CU
    lstm2_kernel<<<1024, 256, 0, stream>>>(x, Wih0, Whh0, bih0, bhh0,
                                           Wih1, Whh1, bih1, bhh1,
                                           Wlin, blin, (float*)d_out);
}

// Round 4
// 542.217 us; speedup vs baseline: 7.2327x; 7.2327x over previous
//
#include <hip/hip_runtime.h>

typedef _Float16 v8h __attribute__((ext_vector_type(8)));
typedef float    v4f __attribute__((ext_vector_type(4)));

#define MFMA16(A,B,C) __builtin_amdgcn_mfma_f32_16x16x32_f16((A),(B),(C),0,0,0)

#define RPB 4
#define TT  256
#define HH  64
#define KST 136        // f16 stride per A row: k 0-63 = ha, 64-127 = hb, 8 pad
#define SGN -1.44269504f   // -log2(e): sigma(z) = rcp(1 + exp2(z*SGN_scaled))
#define GTS -2.88539008f   // -2*log2(e): tanh(z) = 2*sigma(2z)-1
#define TSC2 -2.88539008f  // tanh(c) = 2*rcp(1+exp2(c*TSC2))-1

// R4: R3's __launch_bounds__(256,4) capped the allocator at 64 VGPRs ->
// the 12 stationary v8h weight frags spilled to scratch, reloaded every
// step (FETCH 13GB = 48KB/block-step, 10x regression). Fix: bound (256,2)
// (proven 116-VGPR allocation, <=128 so HW still fits 4 waves/SIMD) +
// grid=1024 (RPB=4). Occupancy comes from the grid, NOT from strangling
// the allocator. Keeps: all-exp2 gates, A-frag dup-read (C rows 4-15 dup
// rows 0-3, no LDS duplication), 1 barrier/step, per-lane pointwise = 2
// rows (8 sig + 2 tanh).
__global__ __launch_bounds__(256, 2)
void lstm2_kernel(const float* __restrict__ x,     // [4096][256]
                  const float* __restrict__ Wih0,  // [256][1]
                  const float* __restrict__ Whh0,  // [256][64]
                  const float* __restrict__ bih0,
                  const float* __restrict__ bhh0,
                  const float* __restrict__ Wih1,  // [256][64]
                  const float* __restrict__ Whh1,  // [256][64]
                  const float* __restrict__ bih1,
                  const float* __restrict__ bhh1,
                  const float* __restrict__ Wlin,  // [64][64]
                  const float* __restrict__ blin,
                  float* __restrict__ out)         // [4096][64]
{
    __shared__ __align__(16) float xl[TT][RPB];        // 4 KB
    __shared__ __align__(16) _Float16 hs[2][RPB][KST]; // 2.1 KB (no dup rows)
    __shared__ float hbF[RPB][HH];                     // 1 KB

    const int tid  = threadIdx.x;
    const int w    = tid >> 6;
    const int l15  = tid & 15;
    const int l3   = tid & 3;          // A-frag row (dup-read: rows 4-15 -> 0-3)
    const int q    = (tid & 63) >> 4;
    const int row0 = (int)blockIdx.x * RPB;
    const int jj   = w * 16 + l15;
    const bool isA = (q < 2);          // q<2: layer-0 lanes; q>=2: layer-1 lanes
    const int  mr  = (q & 1) * 2;      // my pointwise row base (0 or 2), 2 rows

    // coalesced global read, strided (one-time) LDS write
    for (int idx = tid; idx < RPB * TT; idx += 256) {
        int m = idx >> 8, t = idx & 255;
        xl[t][m] = x[(row0 + m) * TT + t];
    }
    for (int idx = tid; idx < 2 * RPB * KST; idx += 256)
        ((_Float16*)hs)[idx] = (_Float16)0.f;

    // sigma on the trans unit; t is the prescaled MFMA acc (= -z*log2e)
    auto sig = [&](float t) -> float {
        return __builtin_amdgcn_rcpf(1.0f + __builtin_exp2f(t));
    };
    // tanh via hardware exp2+rcp (near-exact, no gather)
    auto tanhf_fast = [&](float c) -> float {
        return fmaf(2.f, __builtin_amdgcn_rcpf(1.f + __builtin_exp2f(c * TSC2)), -1.f);
    };

    // ---- register-stationary weights, prescaled into exp2-argument space ----
    float wi0s[4], b0s[4];
    v4f   b1v[4];
    v8h wh0[4][2], wi1[4][2], wh1[4][2];
    #pragma unroll
    for (int tau = 0; tau < 4; tau++) {
        float sc = (tau == 2) ? GTS : SGN;
        int n = tau * 64 + jj;
        wi0s[tau] = Wih0[n] * sc;
        b0s[tau]  = (bih0[n] + bhh0[n]) * sc;
        float b1  = (bih1[n] + bhh1[n]) * sc;
        b1v[tau]  = (v4f){b1, b1, b1, b1};
        #pragma unroll
        for (int kk = 0; kk < 2; kk++) {
            int k0 = kk * 32 + q * 8;   // B-frag: B[k0..k0+7][n=lane&15]
            v8h a, b, c;
            #pragma unroll
            for (int j = 0; j < 8; j++) {
                a[j] = (_Float16)(Whh0[n * HH + k0 + j] * sc);
                b[j] = (_Float16)(Wih1[n * HH + k0 + j] * sc);
                c[j] = (_Float16)(Whh1[n * HH + k0 + j] * sc);
            }
            wh0[tau][kk] = a; wi1[tau][kk] = b; wh1[tau][kk] = c;
        }
    }

    float cs[2] = {0.f, 0.f};  // c-state of MY layer, rows mr..mr+1
    __syncthreads();

    // ---- prologue t=0: ha(0) from x(0) only (written by q<2 lanes) ----
    if (isA) {
        #pragma unroll
        for (int r = 0; r < 2; r++) {
            int m = mr + r;
            float xv = xl[0][m];
            float iv = sig(fmaf(xv, wi0s[0], b0s[0]));
            float gv = fmaf(2.f, sig(fmaf(xv, wi0s[2], b0s[2])), -1.f);
            float ov = sig(fmaf(xv, wi0s[3], b0s[3]));
            cs[r] = iv * gv;
            hs[0][m][jj] = (_Float16)(ov * tanhf_fast(cs[r]));
        }
    }
    __syncthreads();

    // step k: reads buf[p] {ha(k-1), hb(k-2)}, writes buf[pw] {ha(k), hb(k-1)}
    auto step = [&](int k, int p, int pw, bool last) {
        v8h a0 = *(const v8h*)&hs[p][l3][q * 8];          // ha k 0-31
        v8h a1 = *(const v8h*)&hs[p][l3][32 + q * 8];     // ha k 32-63
        v8h b0 = *(const v8h*)&hs[p][l3][64 + q * 8];     // hb k 0-31
        v8h b1 = *(const v8h*)&hs[p][l3][96 + q * 8];     // hb k 32-63
        int kx = (k < TT) ? k : (TT - 1);                 // k=256: junk x, unused
        v4f xv = *(const v4f*)&xl[kx][0];                 // rows 0-3

        v4f acc0[4], acc1[4];
        #pragma unroll
        for (int tau = 0; tau < 4; tau++) {
            #pragma unroll
            for (int r = 0; r < 4; r++) acc0[tau][r] = fmaf(xv[r], wi0s[tau], b0s[tau]);
            acc1[tau] = MFMA16(a0, wi1[tau][0], b1v[tau]);  // bias as C operand
        }
        #pragma unroll
        for (int tau = 0; tau < 4; tau++) {
            acc0[tau] = MFMA16(a0, wh0[tau][0], acc0[tau]);
            acc0[tau] = MFMA16(a1, wh0[tau][1], acc0[tau]);
            acc1[tau] = MFMA16(a1, wi1[tau][1], acc1[tau]);
            acc1[tau] = MFMA16(b0, wh1[tau][0], acc1[tau]);
            acc1[tau] = MFMA16(b1, wh1[tau][1], acc1[tau]);
        }

        // my gates: q<2 -> layer0; q>=2 -> layer1. acc reg index == batch row
        // (C row = q*4+reg; A rows dup mod 4 -> batch row = reg).
        v4f g0 = isA ? acc0[0] : acc1[0];
        v4f g1 = isA ? acc0[1] : acc1[1];
        v4f g2 = isA ? acc0[2] : acc1[2];
        v4f g3 = isA ? acc0[3] : acc1[3];

        // stage 1: all 8 sigma issued together (trans-unit latency overlap)
        float sv0[2], sv1[2], sv2[2], sv3[2];
        #pragma unroll
        for (int r = 0; r < 2; r++) {
            sv0[r] = sig(g0[mr + r]);
            sv1[r] = sig(g1[mr + r]);
            sv2[r] = sig(g2[mr + r]);
            sv3[r] = sig(g3[mr + r]);
        }

        _Float16* wp = &hs[pw][mr][isA ? jj : (64 + jj)];

        // stage 2: c update, trans tanh, h write (single LDS write per value)
        #pragma unroll
        for (int r = 0; r < 2; r++) {
            float iv = sv0[r];
            float fv = sv1[r];
            float gv = fmaf(2.f, sv2[r], -1.f);
            float ov = sv3[r];
            cs[r] = fmaf(fv, cs[r], iv * gv);
            float hv = ov * tanhf_fast(cs[r]);
            wp[r * KST] = (_Float16)hv;
            if (last && !isA) hbF[mr + r][jj] = hv;
        }
        __syncthreads();
    };

    // k = 1..256 (k=256 = layer-1-only epilogue; its ha output junk-but-finite)
    for (int k = 1; k <= TT; k += 2) {
        step(k,     0, 1, false);
        step(k + 1, 1, 0, (k + 1) == TT);
    }

    // ---- out[m][n] = hbF[m][:] . Wlin[n][:] + blin[n] ----
    int m = tid >> 6;             // 0..3
    int n = tid & 63;
    float ao = blin[n];
    #pragma unroll 8
    for (int j = 0; j < HH; j++)
        ao = fmaf(hbF[m][j], Wlin[n * HH + j], ao);
    out[(row0 + m) * HH + n] = ao;
}

extern "C" void kernel_launch(void* const* d_in, const int* in_sizes, int n_in,
                              void* d_out, int out_size, void* d_ws, size_t ws_size,
                              hipStream_t stream) {
    const float* x    = (const float*)d_in[0];
    const float* Wih0 = (const float*)d_in[1];
    const float* Whh0 = (const float*)d_in[2];
    const float* bih0 = (const float*)d_in[3];
    const float* bhh0 = (const float*)d_in[4];
    const float* Wih1 = (const float*)d_in[5];
    const float* Whh1 = (const float*)d_in[6];
    const float* bih1 = (const float*)d_in[7];
    const float* bhh1 = (const float*)d_in[8];
    const float* Wlin = (const float*)d_in[9];
    const float* blin = (const float*)d_in[10];
    // 4096 rows / 4 per block = 1024 blocks; VGPR<=128 -> 4 blocks/CU resident
    lstm2_kernel<<<1024, 256, 0, stream>>>(x, Wih0, Whh0, bih0, bhh0,
                                           Wih1, Whh1, bih1, bhh1,
                                           Wlin, blin, (float*)d_out);
}

// Round 5
// 370.757 us; speedup vs baseline: 10.5776x; 1.4625x over previous
//
#include <hip/hip_runtime.h>

typedef _Float16 v8h __attribute__((ext_vector_type(8)));
typedef float    v4f __attribute__((ext_vector_type(4)));

#define MFMA16(A,B,C) __builtin_amdgcn_mfma_f32_16x16x32_f16((A),(B),(C),0,0,0)

#define RPB 8
#define TT  256
#define HH  64
#define KST 136      // f16 stride per A row: k 0-63 = ha, 64-127 = hb, 8 pad
#define SG  256.0f   // sigmoid LUT index scale (table step 1/256)
#define IOFF 4096.5f // LUT index center + 0.5 NN rounding offset
#define SGN -1.44269504f   // -log2(e): sigma(z) = rcp(1 + exp2(z*SGN))
#define GTS -2.88539008f   // -2*log2(e): tanh(z) = 2*sigma(2z)-1
#define TSC2 -2.88539008f  // tanh(c) = 2*rcp(1+exp2(c*TSC2))-1

// R5: pipe-balanced activations on the R0 (318us) base. The 4096
// sigmoids/block-step cost ~1000 LDS-pipe cyc as LUT gathers (R0: conflicts
// 4.4e7, VALU 50%) or ~1500 VALU cyc as quarter-rate exp2 (R1: VALU 70%,
// slower). Split: i,f gates -> LUT (8 gathers/lane, issued first); g,o ->
// exp2 on trans unit (overlaps the in-flight gathers); tanh(c) stays exp2.
// Per-tau prescale: tau0,1 x256+IOFF (LUT space), tau2 x-2log2e, tau3
// x-log2e. Occupancy is reg-bound at 2 blocks/CU (R3/R4: VGPR_Count
// excludes acc regs; ~180 total/wave) -> keep RPB=8, grid 512, bounds(256,2).
__global__ __launch_bounds__(256, 2)
void lstm2_kernel(const float* __restrict__ x,     // [4096][256]
                  const float* __restrict__ Wih0,  // [256][1]
                  const float* __restrict__ Whh0,  // [256][64]
                  const float* __restrict__ bih0,
                  const float* __restrict__ bhh0,
                  const float* __restrict__ Wih1,  // [256][64]
                  const float* __restrict__ Whh1,  // [256][64]
                  const float* __restrict__ bih1,
                  const float* __restrict__ bhh1,
                  const float* __restrict__ Wlin,  // [64][64]
                  const float* __restrict__ blin,
                  float* __restrict__ out)         // [4096][64]
{
    __shared__ float xl[TT][RPB];                      // 8 KB
    __shared__ __align__(16) _Float16 hs[2][RPB][KST]; // 4.25 KB (no dup rows)
    __shared__ float hbF[RPB][HH];                     // 2 KB
    __shared__ float lut[8192];                        // 32 KB sigma table

    const int tid  = threadIdx.x;
    const int w    = tid >> 6;
    const int l15  = tid & 15;
    const int l7   = tid & 7;          // A-frag row (dup-read: rows 8-15 -> 0-7)
    const int q    = (tid & 63) >> 4;
    const int row0 = (int)blockIdx.x * RPB;
    const int jj   = w * 16 + l15;
    const bool isA = (q < 2);          // q<2: layer-0 lanes; q>=2: layer-1 lanes
    const int  mr  = (q & 1) * 4;      // my pointwise row base (0 or 4)

    for (int idx = tid; idx < RPB * TT; idx += 256) {
        int m = idx & 7, t = idx >> 3;
        xl[t][m] = x[(row0 + m) * TT + t];
    }
    for (int idx = tid; idx < 2 * RPB * KST; idx += 256)
        ((_Float16*)hs)[idx] = (_Float16)0.f;
    for (int i = tid; i < 8192; i += 256)
        lut[i] = 1.0f / (1.0f + __expf(-(i - 4096) * (1.0f / 256.0f)));

    // sigma via nearest-neighbor LUT; f is a pre-scaled index (z*256+4096.5)
    auto lutv = [&](float f) -> float {
        f = __builtin_amdgcn_fmed3f(f, 0.0f, 8191.0f);
        return lut[(int)f];
    };
    // sigma on the trans unit; t is the prescaled MFMA acc (= -z*log2e)
    auto sig = [&](float t) -> float {
        return __builtin_amdgcn_rcpf(1.0f + __builtin_exp2f(t));
    };
    // tanh via hardware exp2+rcp (near-exact, no gather)
    auto tanhf_fast = [&](float c) -> float {
        return fmaf(2.f, __builtin_amdgcn_rcpf(1.f + __builtin_exp2f(c * TSC2)), -1.f);
    };

    // ---- register-stationary weights, prescaled per gate ----
    // tau 0 (i), 1 (f): LUT index space (x256, bias +IOFF)
    // tau 2 (g): exp2 space x-2log2e;  tau 3 (o): exp2 space x-log2e
    float wi0s[4], b0s[4];
    v4f   b1v[4];
    v8h wh0[4][2], wi1[4][2], wh1[4][2];
    #pragma unroll
    for (int tau = 0; tau < 4; tau++) {
        float sc  = (tau < 2) ? SG : ((tau == 2) ? GTS : SGN);
        float off = (tau < 2) ? IOFF : 0.0f;
        int n = tau * 64 + jj;
        wi0s[tau] = Wih0[n] * sc;
        b0s[tau]  = (bih0[n] + bhh0[n]) * sc + off;
        float b1  = (bih1[n] + bhh1[n]) * sc + off;
        b1v[tau]  = (v4f){b1, b1, b1, b1};
        #pragma unroll
        for (int kk = 0; kk < 2; kk++) {
            int k0 = kk * 32 + q * 8;   // B-frag: B[k0..k0+7][n=lane&15]
            v8h a, b, c;
            #pragma unroll
            for (int j = 0; j < 8; j++) {
                a[j] = (_Float16)(Whh0[n * HH + k0 + j] * sc);
                b[j] = (_Float16)(Wih1[n * HH + k0 + j] * sc);
                c[j] = (_Float16)(Whh1[n * HH + k0 + j] * sc);
            }
            wh0[tau][kk] = a; wi1[tau][kk] = b; wh1[tau][kk] = c;
        }
    }

    float cs[4] = {0.f, 0.f, 0.f, 0.f};  // c-state of MY layer, rows mr..mr+3
    __syncthreads();

    // ---- prologue t=0: ha(0) from x(0) only (written by q<2 lanes) ----
    if (isA) {
        #pragma unroll
        for (int r = 0; r < 4; r++) {
            int m = mr + r;
            float xv = xl[0][m];
            float iv = lutv(fmaf(xv, wi0s[0], b0s[0]));
            float gv = fmaf(2.f, sig(fmaf(xv, wi0s[2], b0s[2])), -1.f);
            float ov = sig(fmaf(xv, wi0s[3], b0s[3]));
            cs[r] = iv * gv;
            hs[0][m][jj] = (_Float16)(ov * tanhf_fast(cs[r]));
        }
    }
    __syncthreads();

    // step k: reads buf[p] {ha(k-1), hb(k-2)}, writes buf[pw] {ha(k), hb(k-1)}
    auto step = [&](int k, int p, int pw, bool last) {
        v8h a0 = *(const v8h*)&hs[p][l7][q * 8];          // ha k 0-31
        v8h a1 = *(const v8h*)&hs[p][l7][32 + q * 8];     // ha k 32-63
        v8h b0 = *(const v8h*)&hs[p][l7][64 + q * 8];     // hb k 0-31
        v8h b1 = *(const v8h*)&hs[p][l7][96 + q * 8];     // hb k 32-63
        int kx = (k < TT) ? k : (TT - 1);                 // k=256: junk x, unused
        v4f xv = *(const v4f*)&xl[kx][mr];

        v4f acc0[4], acc1[4];
        #pragma unroll
        for (int tau = 0; tau < 4; tau++) {
            #pragma unroll
            for (int r = 0; r < 4; r++) acc0[tau][r] = fmaf(xv[r], wi0s[tau], b0s[tau]);
            acc1[tau] = MFMA16(a0, wi1[tau][0], b1v[tau]);  // bias as C operand
        }
        #pragma unroll
        for (int tau = 0; tau < 4; tau++) {
            acc0[tau] = MFMA16(a0, wh0[tau][0], acc0[tau]);
            acc0[tau] = MFMA16(a1, wh0[tau][1], acc0[tau]);
            acc1[tau] = MFMA16(a1, wi1[tau][1], acc1[tau]);
            acc1[tau] = MFMA16(b0, wh1[tau][0], acc1[tau]);
            acc1[tau] = MFMA16(b1, wh1[tau][1], acc1[tau]);
        }

        // my gates: q<2 -> layer0 (C rows 0-7); q>=2 -> layer1 (C rows 8-15)
        v4f g0 = isA ? acc0[0] : acc1[0];
        v4f g1 = isA ? acc0[1] : acc1[1];
        v4f g2 = isA ? acc0[2] : acc1[2];
        v4f g3 = isA ? acc0[3] : acc1[3];

        // stage 1a: i,f via LUT — all 8 gathers issued first (in flight)
        float sv0[4], sv1[4];
        #pragma unroll
        for (int r = 0; r < 4; r++) {
            sv0[r] = lutv(g0[r]);
            sv1[r] = lutv(g1[r]);
        }
        // stage 1b: g,o via exp2 on the trans unit — overlaps the gathers
        float sv2[4], sv3[4];
        #pragma unroll
        for (int r = 0; r < 4; r++) {
            sv2[r] = sig(g2[r]);
            sv3[r] = sig(g3[r]);
        }

        _Float16* wp = &hs[pw][mr][isA ? jj : (64 + jj)];

        // stage 2: c update, trans tanh, h write (single LDS write per value)
        #pragma unroll
        for (int r = 0; r < 4; r++) {
            float iv = sv0[r];
            float fv = sv1[r];
            float gv = fmaf(2.f, sv2[r], -1.f);
            float ov = sv3[r];
            cs[r] = fmaf(fv, cs[r], iv * gv);
            float hv = ov * tanhf_fast(cs[r]);
            wp[r * KST] = (_Float16)hv;
            if (last && !isA) hbF[mr + r][jj] = hv;
        }
        __syncthreads();
    };

    // k = 1..256 (k=256 = layer-1-only epilogue; its ha output junk-but-finite)
    for (int k = 1; k <= TT; k += 2) {
        step(k,     0, 1, false);
        step(k + 1, 1, 0, (k + 1) == TT);
    }

    // ---- out[m][n] = hbF[m][:] . Wlin[n][:] + blin[n] ----
    int m  = tid >> 5;            // 0..7
    int n0 = (tid & 31) * 2;
    float a0o = blin[n0], a1o = blin[n0 + 1];
    #pragma unroll 8
    for (int j = 0; j < HH; j++) {
        float h = hbF[m][j];
        a0o = fmaf(h, Wlin[(n0 + 0) * HH + j], a0o);
        a1o = fmaf(h, Wlin[(n0 + 1) * HH + j], a1o);
    }
    out[(row0 + m) * HH + n0]     = a0o;
    out[(row0 + m) * HH + n0 + 1] = a1o;
}

extern "C" void kernel_launch(void* const* d_in, const int* in_sizes, int n_in,
                              void* d_out, int out_size, void* d_ws, size_t ws_size,
                              hipStream_t stream) {
    const float* x    = (const float*)d_in[0];
    const float* Wih0 = (const float*)d_in[1];
    const float* Whh0 = (const float*)d_in[2];
    const float* bih0 = (const float*)d_in[3];
    const float* bhh0 = (const float*)d_in[4];
    const float* Wih1 = (const float*)d_in[5];
    const float* Whh1 = (const float*)d_in[6];
    const float* bih1 = (const float*)d_in[7];
    const float* bhh1 = (const float*)d_in[8];
    const float* Wlin = (const float*)d_in[9];
    const float* blin = (const float*)d_in[10];
    // 4096 rows / 8 per block = 512 blocks = 2 blocks/CU (reg-bound ceiling)
    lstm2_kernel<<<512, 256, 0, stream>>>(x, Wih0, Whh0, bih0, bhh0,
                                          Wih1, Whh1, bih1, bhh1,
                                          Wlin, blin, (float*)d_out);
}

// Round 6
// 312.500 us; speedup vs baseline: 12.5495x; 1.1864x over previous
//
#include <hip/hip_runtime.h>

typedef _Float16 v8h __attribute__((ext_vector_type(8)));
typedef float    v4f __attribute__((ext_vector_type(4)));

#define MFMA16(A,B,C) __builtin_amdgcn_mfma_f32_16x16x32_f16((A),(B),(C),0,0,0)

#define RPB 16
#define TT  256
#define HH  64
#define KST 136      // f16 stride per A row: k 0-63 = ha, 64-127 = hb, 8 pad
#define SG  256.0f   // sigmoid LUT index scale (table step 1/256)
#define TG  512.0f   // g-gate tanh index scale (tanh(z)=2*sigma(2z)-1)
#define IOFF 4096.5f // LUT index center + 0.5 NN rounding offset
#define TSC2 -2.88539008f // -2*log2(e): tanh(c)=2*rcp(1+exp2(c*TSC2))-1

// R6: kill the 2x MFMA duplication. R0's l7 dup-read made C rows 8-15
// copies of rows 0-7 (paying 16-row MFMAs for 8 rows); MFMA pipe = 930
// cyc/SIMD-step = 28% util, all halvable. Now: 16 REAL batch rows per
// block (A row = lane&15), 512 threads = 8 waves split by layer (w<4:
// layer0, 8 MFMAs + x-init; w>=4: layer1, 16 MFMAs) -> each SIMD runs one
// L0 + one L1 wave, MFMA pipe/SIMD-step 930->465. Per-lane pointwise
// unchanged (16 LUT gathers + 4 tanh = R0's proven optimum; R1/R5 showed
// exp2 sigmoids lose). Grid 256 = 1 block/CU, 8 waves. bounds(512,2) caps
// VGPR at 256 (~170 needed, no spill; R3 lesson: never strangle allocator).
__global__ __launch_bounds__(512, 2)
void lstm2_kernel(const float* __restrict__ x,     // [4096][256]
                  const float* __restrict__ Wih0,  // [256][1]
                  const float* __restrict__ Whh0,  // [256][64]
                  const float* __restrict__ bih0,
                  const float* __restrict__ bhh0,
                  const float* __restrict__ Wih1,  // [256][64]
                  const float* __restrict__ Whh1,  // [256][64]
                  const float* __restrict__ bih1,
                  const float* __restrict__ bhh1,
                  const float* __restrict__ Wlin,  // [64][64]
                  const float* __restrict__ blin,
                  float* __restrict__ out)         // [4096][64]
{
    __shared__ float xl[TT][RPB];                      // 16 KB
    __shared__ __align__(16) _Float16 hs[2][RPB][KST]; // 8.5 KB
    __shared__ float hbF[RPB][HH];                     // 4 KB
    __shared__ float lut[8192];                        // 32 KB sigma table

    const int tid  = threadIdx.x;
    const int w    = tid >> 6;         // wave 0..7
    const int l15  = tid & 15;         // A-frag row = batch row (no dup)
    const int q    = (tid & 63) >> 4;  // k-group / pointwise row-quad
    const int row0 = (int)blockIdx.x * RPB;
    const int jj   = (w & 3) * 16 + l15;  // gate column 0..63
    const bool isA = (w < 4);          // wave-uniform: layer0 vs layer1
    const int  mr  = q * 4;            // my pointwise row base (0,4,8,12)

    for (int idx = tid; idx < RPB * TT; idx += 512) {
        int m = idx & 15, t = idx >> 4;
        xl[t][m] = x[(row0 + m) * TT + t];
    }
    for (int idx = tid; idx < 2 * RPB * KST; idx += 512)
        ((_Float16*)hs)[idx] = (_Float16)0.f;
    for (int i = tid; i < 8192; i += 512)
        lut[i] = 1.0f / (1.0f + __expf(-(i - 4096) * (1.0f / 256.0f)));

    // sigma via nearest-neighbor LUT; f is a pre-scaled index (z*256+4096.5)
    auto lutv = [&](float f) -> float {
        f = __builtin_amdgcn_fmed3f(f, 0.0f, 8191.0f);
        return lut[(int)f];
    };
    // tanh via hardware exp2+rcp (near-exact, no gather)
    auto tanhf_fast = [&](float c) -> float {
        return fmaf(2.f, __builtin_amdgcn_rcpf(1.f + __builtin_exp2f(c * TSC2)), -1.f);
    };

    // ---- register-stationary weights (only MY layer's), LUT index space ----
    float wi0s[4], b0s[4];
    v8h   wh0[4][2];
    v4f   b1v[4];
    v8h   wi1[4][2], wh1[4][2];
    if (isA) {
        #pragma unroll
        for (int tau = 0; tau < 4; tau++) {
            float sc = (tau == 2) ? TG : SG;
            int n = tau * 64 + jj;
            wi0s[tau] = Wih0[n] * sc;
            b0s[tau]  = (bih0[n] + bhh0[n]) * sc + IOFF;
            #pragma unroll
            for (int kk = 0; kk < 2; kk++) {
                int k0 = kk * 32 + q * 8;   // B-frag: B[k0..k0+7][n=lane&15]
                v8h a;
                #pragma unroll
                for (int j = 0; j < 8; j++)
                    a[j] = (_Float16)(Whh0[n * HH + k0 + j] * sc);
                wh0[tau][kk] = a;
            }
        }
    } else {
        #pragma unroll
        for (int tau = 0; tau < 4; tau++) {
            float sc = (tau == 2) ? TG : SG;
            int n = tau * 64 + jj;
            float b1 = (bih1[n] + bhh1[n]) * sc + IOFF;
            b1v[tau] = (v4f){b1, b1, b1, b1};
            #pragma unroll
            for (int kk = 0; kk < 2; kk++) {
                int k0 = kk * 32 + q * 8;
                v8h b, c;
                #pragma unroll
                for (int j = 0; j < 8; j++) {
                    b[j] = (_Float16)(Wih1[n * HH + k0 + j] * sc);
                    c[j] = (_Float16)(Whh1[n * HH + k0 + j] * sc);
                }
                wi1[tau][kk] = b; wh1[tau][kk] = c;
            }
        }
    }

    float cs[4] = {0.f, 0.f, 0.f, 0.f};  // c-state of MY layer, rows mr..mr+3
    __syncthreads();

    // ---- prologue t=0: ha(0) from x(0) only (layer-0 waves) ----
    if (isA) {
        #pragma unroll
        for (int r = 0; r < 4; r++) {
            int m = mr + r;
            float xv = xl[0][m];
            float iv = lutv(fmaf(xv, wi0s[0], b0s[0]));
            float gv = fmaf(2.f, lutv(fmaf(xv, wi0s[2], b0s[2])), -1.f);
            float ov = lutv(fmaf(xv, wi0s[3], b0s[3]));
            cs[r] = iv * gv;
            hs[0][m][jj] = (_Float16)(ov * tanhf_fast(cs[r]));
        }
    }
    __syncthreads();

    // step k: reads buf[p] {ha(k-1), hb(k-2)}, writes buf[pw] {ha(k), hb(k-1)}
    auto step = [&](int k, int p, int pw, bool last) {
        if (isA) {
            // ---- layer 0: 8 MFMAs, x via rank-1 fmaf init ----
            v8h a0 = *(const v8h*)&hs[p][l15][q * 8];          // ha k 0-31
            v8h a1 = *(const v8h*)&hs[p][l15][32 + q * 8];     // ha k 32-63
            int kx = (k < TT) ? k : (TT - 1);                  // k=256: junk
            v4f xv = *(const v4f*)&xl[kx][mr];

            v4f acc[4];
            #pragma unroll
            for (int tau = 0; tau < 4; tau++) {
                #pragma unroll
                for (int r = 0; r < 4; r++)
                    acc[tau][r] = fmaf(xv[r], wi0s[tau], b0s[tau]);
            }
            #pragma unroll
            for (int tau = 0; tau < 4; tau++) {
                acc[tau] = MFMA16(a0, wh0[tau][0], acc[tau]);
                acc[tau] = MFMA16(a1, wh0[tau][1], acc[tau]);
            }
            // all 16 gathers issued together (one latency round)
            float sv0[4], sv1[4], sv2[4], sv3[4];
            #pragma unroll
            for (int r = 0; r < 4; r++) {
                sv0[r] = lutv(acc[0][r]);
                sv1[r] = lutv(acc[1][r]);
                sv2[r] = lutv(acc[2][r]);
                sv3[r] = lutv(acc[3][r]);
            }
            _Float16* wp = &hs[pw][mr][jj];
            #pragma unroll
            for (int r = 0; r < 4; r++) {
                float iv = sv0[r], fv = sv1[r];
                float gv = fmaf(2.f, sv2[r], -1.f);
                float ov = sv3[r];
                cs[r] = fmaf(fv, cs[r], iv * gv);
                wp[r * KST] = (_Float16)(ov * tanhf_fast(cs[r]));
            }
        } else {
            // ---- layer 1: 16 MFMAs over [ha | hb], bias as C operand ----
            v8h a0 = *(const v8h*)&hs[p][l15][q * 8];          // ha k 0-31
            v8h a1 = *(const v8h*)&hs[p][l15][32 + q * 8];     // ha k 32-63
            v8h b0 = *(const v8h*)&hs[p][l15][64 + q * 8];     // hb k 0-31
            v8h b1 = *(const v8h*)&hs[p][l15][96 + q * 8];     // hb k 32-63

            v4f acc[4];
            #pragma unroll
            for (int tau = 0; tau < 4; tau++)
                acc[tau] = MFMA16(a0, wi1[tau][0], b1v[tau]);
            #pragma unroll
            for (int tau = 0; tau < 4; tau++) {
                acc[tau] = MFMA16(a1, wi1[tau][1], acc[tau]);
                acc[tau] = MFMA16(b0, wh1[tau][0], acc[tau]);
                acc[tau] = MFMA16(b1, wh1[tau][1], acc[tau]);
            }
            float sv0[4], sv1[4], sv2[4], sv3[4];
            #pragma unroll
            for (int r = 0; r < 4; r++) {
                sv0[r] = lutv(acc[0][r]);
                sv1[r] = lutv(acc[1][r]);
                sv2[r] = lutv(acc[2][r]);
                sv3[r] = lutv(acc[3][r]);
            }
            _Float16* wp = &hs[pw][mr][64 + jj];
            #pragma unroll
            for (int r = 0; r < 4; r++) {
                float iv = sv0[r], fv = sv1[r];
                float gv = fmaf(2.f, sv2[r], -1.f);
                float ov = sv3[r];
                cs[r] = fmaf(fv, cs[r], iv * gv);
                float hv = ov * tanhf_fast(cs[r]);
                wp[r * KST] = (_Float16)hv;
                if (last) hbF[mr + r][jj] = hv;
            }
        }
        __syncthreads();
    };

    // k = 1..256 (k=256 = layer-1-only epilogue; its ha output junk-but-finite)
    for (int k = 1; k <= TT; k += 2) {
        step(k,     0, 1, false);
        step(k + 1, 1, 0, (k + 1) == TT);
    }

    // ---- out[m][n] = hbF[m][:] . Wlin[n][:] + blin[n] ----
    int m = tid >> 5;             // 0..15
    int n0 = (tid & 31) * 2;
    float a0o = blin[n0], a1o = blin[n0 + 1];
    #pragma unroll 8
    for (int j = 0; j < HH; j++) {
        float h = hbF[m][j];
        a0o = fmaf(h, Wlin[(n0 + 0) * HH + j], a0o);
        a1o = fmaf(h, Wlin[(n0 + 1) * HH + j], a1o);
    }
    out[(row0 + m) * HH + n0]     = a0o;
    out[(row0 + m) * HH + n0 + 1] = a1o;
}

extern "C" void kernel_launch(void* const* d_in, const int* in_sizes, int n_in,
                              void* d_out, int out_size, void* d_ws, size_t ws_size,
                              hipStream_t stream) {
    const float* x    = (const float*)d_in[0];
    const float* Wih0 = (const float*)d_in[1];
    const float* Whh0 = (const float*)d_in[2];
    const float* bih0 = (const float*)d_in[3];
    const float* bhh0 = (const float*)d_in[4];
    const float* Wih1 = (const float*)d_in[5];
    const float* Whh1 = (const float*)d_in[6];
    const float* bih1 = (const float*)d_in[7];
    const float* bhh1 = (const float*)d_in[8];
    const float* Wlin = (const float*)d_in[9];
    const float* blin = (const float*)d_in[10];
    // 4096 rows / 16 per block = 256 blocks = 1 block/CU, 8 waves (2/SIMD)
    lstm2_kernel<<<256, 512, 0, stream>>>(x, Wih0, Whh0, bih0, bhh0,
                                          Wih1, Whh1, bih1, bhh1,
                                          Wlin, blin, (float*)d_out);
}